// Round 3
// baseline (903.770 us; speedup 1.0000x reference)
//
#include <hip/hip_runtime.h>
#include <math.h>

#define F 128
#define R 16
#define O 12
#define NB 32   // nodes per block in fused MLP

// ---------------- small utility kernels ----------------
__global__ void zero_int_kernel(int* __restrict__ p, int n) {
    int i = blockIdx.x * blockDim.x + threadIdx.x;
    if (i < n) p[i] = 0;
}

// ---------------- CSR build: histogram ----------------
__global__ __launch_bounds__(256) void hist_kernel(
    const int* __restrict__ idx, int* __restrict__ cnt, int E)
{
    int i = blockIdx.x * blockDim.x + threadIdx.x;
    int stride = gridDim.x * blockDim.x;
    for (; i < E; i += stride) atomicAdd(&cnt[idx[i]], 1);
}

// ---------------- CSR build: exclusive scan (single block) ----------------
__global__ __launch_bounds__(1024) void scan_kernel(
    const int* __restrict__ cnt, int* __restrict__ off,
    int* __restrict__ cur, int N, int E)
{
    __shared__ int part[1024];
    int t = threadIdx.x;
    const int per = (N + 1023) / 1024;
    int s0 = t * per;
    int s = 0;
    for (int i = 0; i < per; i++) { int k = s0 + i; if (k < N) s += cnt[k]; }
    part[t] = s;
    __syncthreads();
    for (int d = 1; d < 1024; d <<= 1) {
        int v = (t >= d) ? part[t - d] : 0;
        __syncthreads();
        part[t] += v;
        __syncthreads();
    }
    int run = (t == 0) ? 0 : part[t - 1];
    for (int i = 0; i < per; i++) {
        int k = s0 + i;
        if (k < N) { off[k] = run; cur[k] = run; run += cnt[k]; }
    }
    if (t == 0) off[N] = E;
}

// ---------------- CSR build: fill edge lists ----------------
__global__ __launch_bounds__(256) void fill_kernel(
    const int* __restrict__ idx, int* __restrict__ cur,
    int* __restrict__ csr, int E)
{
    int i = blockIdx.x * blockDim.x + threadIdx.x;
    int stride = gridDim.x * blockDim.x;
    for (; i < E; i += stride) {
        int n = idx[i];
        int p = atomicAdd(&cur[n], 1);
        csr[p] = i;
    }
}

__device__ __forceinline__ float dot16(const float4* r, const float4* Wv) {
    float s = 0.f;
    #pragma unroll
    for (int q = 0; q < 4; q++)
        s += r[q].x * Wv[q].x + r[q].y * Wv[q].y + r[q].z * Wv[q].z + r[q].w * Wv[q].w;
    return s;
}

// ---------------- fused rbf-linear * gate -> GATHER (no atomics) ----------------
// One wave per node; lane owns features 2l,2l+1. CSR entries for the node are
// loaded lane-parallel (one coalesced read per 64 edges) and distributed via
// __shfl, so edge addresses come from registers -> compiler can pipeline the
// 20 independent loads of the next 4-edge group over the current group's FMAs.
__global__ __launch_bounds__(256) void gather_kernel(
    const float* __restrict__ m, const float* __restrict__ rbf,
    const int* __restrict__ csr, const int* __restrict__ off,
    const float* __restrict__ Wrbf, float* __restrict__ A, int N)
{
    int lane = threadIdx.x & 63;
    int w = threadIdx.x >> 6;
    int n = blockIdx.x * 4 + w;
    if (n >= N) return;

    int f0 = lane << 1;
    float4 W0[4], W1[4];
    #pragma unroll
    for (int q = 0; q < 4; q++) {
        W0[q] = *(const float4*)(Wrbf + (size_t)f0 * R + q * 4);
        W1[q] = *(const float4*)(Wrbf + (size_t)(f0 + 1) * R + q * 4);
    }

    float a0 = 0.f, a1 = 0.f;
    int jb = off[n], je = off[n + 1];

    for (int base = jb; base < je; base += 64) {
        int cnt = min(64, je - base);
        int ec = (base + lane < je) ? csr[base + lane] : 0;
        int jj = 0;
        for (; jj + 4 <= cnt; jj += 4) {
            int e0 = __shfl(ec, jj);
            int e1 = __shfl(ec, jj + 1);
            int e2 = __shfl(ec, jj + 2);
            int e3 = __shfl(ec, jj + 3);
            float2 m0 = *(const float2*)(m + (size_t)e0 * F + f0);
            float2 m1 = *(const float2*)(m + (size_t)e1 * F + f0);
            float2 m2 = *(const float2*)(m + (size_t)e2 * F + f0);
            float2 m3 = *(const float2*)(m + (size_t)e3 * F + f0);
            float4 r0[4], r1[4], r2[4], r3[4];
            #pragma unroll
            for (int q = 0; q < 4; q++) {
                r0[q] = ((const float4*)(rbf + (size_t)e0 * R))[q];
                r1[q] = ((const float4*)(rbf + (size_t)e1 * R))[q];
                r2[q] = ((const float4*)(rbf + (size_t)e2 * R))[q];
                r3[q] = ((const float4*)(rbf + (size_t)e3 * R))[q];
            }
            a0 += dot16(r0, W0) * m0.x;  a1 += dot16(r0, W1) * m0.y;
            a0 += dot16(r1, W0) * m1.x;  a1 += dot16(r1, W1) * m1.y;
            a0 += dot16(r2, W0) * m2.x;  a1 += dot16(r2, W1) * m2.y;
            a0 += dot16(r3, W0) * m3.x;  a1 += dot16(r3, W1) * m3.y;
        }
        for (; jj < cnt; jj++) {
            int e0 = __shfl(ec, jj);
            float2 m0 = *(const float2*)(m + (size_t)e0 * F + f0);
            float4 r0[4];
            #pragma unroll
            for (int q = 0; q < 4; q++)
                r0[q] = ((const float4*)(rbf + (size_t)e0 * R))[q];
            a0 += dot16(r0, W0) * m0.x;
            a1 += dot16(r0, W1) * m0.y;
        }
    }

    *(float2*)(A + (size_t)n * F + f0) = make_float2(a0, a1);
}

// ---------------- fused MLP (3 layers) + projection ----------------
// 32 nodes per block, 625 blocks (exact). Weights staged per layer into 64KB
// LDS; activations in 16KB LDS updated IN-PLACE: row (i+16k) is read and
// written only by the 16 lanes {t = i*16+j} which live in ONE wave ->
// lockstep in-order execution makes in-place safe with no inter-layer sync.
// LDS total 80KB -> 2 blocks/CU.
__global__ __launch_bounds__(256) void mlp_fused(
    const float* __restrict__ A, const float* __restrict__ dW,
    const float* __restrict__ db, const float* __restrict__ Wout,
    float* __restrict__ out, int N)
{
    __shared__ float Ws[F * F];     // 64 KB
    __shared__ float act[NB * F];   // 16 KB
    int t = threadIdx.x;
    int base = blockIdx.x * NB;
    int j = t & 15, i = t >> 4;

    int  n0[2]; bool ok[2];
    #pragma unroll
    for (int k = 0; k < 2; k++) { n0[k] = base + i + 16 * k; ok[k] = n0[k] < N; }

    for (int l = 0; l < 3; l++) {
        __syncthreads();   // previous readers of Ws done (no-op at l=0)
        for (int s = t; s < F * F / 4; s += 256) {
            int g = s >> 5, c = s & 31;
            float4 v = *(const float4*)(dW + (size_t)l * F * F + g * F + (c << 2));
            *(float4*)(Ws + g * F + ((c ^ (g & 31)) << 2)) = v;
        }
        __syncthreads();

        float acc[2][8];
        #pragma unroll
        for (int k = 0; k < 2; k++)
            #pragma unroll
            for (int mm = 0; mm < 8; mm++) acc[k][mm] = 0.f;

        for (int c = 0; c < 32; c++) {
            int f = c << 2;
            float4 av[2];
            #pragma unroll
            for (int k = 0; k < 2; k++) {
                if (l == 0)
                    av[k] = ok[k] ? *(const float4*)(A + (size_t)n0[k] * F + f)
                                  : make_float4(0.f, 0.f, 0.f, 0.f);
                else
                    av[k] = *(const float4*)(act + (i + 16 * k) * F + f);
            }
            float4 wv[8];
            #pragma unroll
            for (int mm = 0; mm < 8; mm++) {
                int g = j + 16 * mm;
                wv[mm] = *(const float4*)(Ws + g * F + ((c ^ (g & 31)) << 2));
            }
            #pragma unroll
            for (int k = 0; k < 2; k++)
                #pragma unroll
                for (int mm = 0; mm < 8; mm++)
                    acc[k][mm] += av[k].x * wv[mm].x + av[k].y * wv[mm].y +
                                  av[k].z * wv[mm].z + av[k].w * wv[mm].w;
        }

        #pragma unroll
        for (int mm = 0; mm < 8; mm++) {
            int g = j + 16 * mm;
            float bias = db[l * F + g];
            #pragma unroll
            for (int k = 0; k < 2; k++) {
                float x = acc[k][mm] + bias;
                act[(i + 16 * k) * F + g] = x / (1.f + __expf(-x));
            }
        }
        // no sync: act rows are wave-local
    }

    // ---- projection ----
    __syncthreads();                 // all waves done writing act
    for (int s = t; s < O * F / 4; s += 256)
        ((float4*)Ws)[s] = ((const float4*)Wout)[s];
    __syncthreads();

    int nl = t >> 3;                 // 0..31
    int oq = t & 7;
    int n = base + nl;
    if (n < N) {
        float s0 = 0.f, s1 = 0.f;
        for (int f = 0; f < F; f += 4) {
            float4 a  = *(const float4*)(act + nl * F + f);
            float4 w0 = *(const float4*)(Ws + oq * F + f);
            s0 += a.x * w0.x + a.y * w0.y + a.z * w0.z + a.w * w0.w;
            if (oq < 4) {
                float4 w1 = *(const float4*)(Ws + (8 + oq) * F + f);
                s1 += a.x * w1.x + a.y * w1.y + a.z * w1.z + a.w * w1.w;
            }
        }
        out[(size_t)n * O + oq] = s0;
        if (oq < 4) out[(size_t)n * O + 8 + oq] = s1;
    }
}

extern "C" void kernel_launch(void* const* d_in, const int* in_sizes, int n_in,
                              void* d_out, int out_size, void* d_ws, size_t ws_size,
                              hipStream_t stream)
{
    const float* m    = (const float*)d_in[0];
    const float* rbf  = (const float*)d_in[1];
    const int*   aei  = (const int*)d_in[2];
    const float* Wrbf = (const float*)d_in[3];
    const float* dW   = (const float*)d_in[4];
    const float* db   = (const float*)d_in[5];
    const float* Wout = (const float*)d_in[6];
    float* out = (float*)d_out;

    int E = in_sizes[0] / F;     // 640000
    int N = out_size / O;        // 20000

    // ws layout: A [N*F floats] | csr[E] | cnt[N] | cur[N] | off[N+1]
    float* A = (float*)d_ws;
    int* csr = (int*)(A + (size_t)N * F);
    int* cnt = csr + E;
    int* cur = cnt + N;
    int* off = cur + N;

    const int* idx1 = aei + E;   // row 1 = receiving atoms

    zero_int_kernel<<<(N + 255) / 256, 256, 0, stream>>>(cnt, N);
    hist_kernel<<<1024, 256, 0, stream>>>(idx1, cnt, E);
    scan_kernel<<<1, 1024, 0, stream>>>(cnt, off, cur, N, E);
    fill_kernel<<<1024, 256, 0, stream>>>(idx1, cur, csr, E);
    gather_kernel<<<(N + 3) / 4, 256, 0, stream>>>(m, rbf, csr, off, Wrbf, A, N);

    mlp_fused<<<(N + NB - 1) / NB, 256, 0, stream>>>(A, dW, db, Wout, out, N);
}

// Round 4
// 794.621 us; speedup vs baseline: 1.1374x; 1.1374x over previous
//
#include <hip/hip_runtime.h>
#include <math.h>

#define F 128
#define R 16
#define O 12
#define NB 32   // nodes per block in fused MLP

// ---------------- small utility kernels ----------------
__global__ void zero_int_kernel(int* __restrict__ p, int n) {
    int i = blockIdx.x * blockDim.x + threadIdx.x;
    if (i < n) p[i] = 0;
}

// ---------------- CSR build: histogram ----------------
__global__ __launch_bounds__(256) void hist_kernel(
    const int* __restrict__ idx, int* __restrict__ cnt, int E)
{
    int i = blockIdx.x * blockDim.x + threadIdx.x;
    int stride = gridDim.x * blockDim.x;
    for (; i < E; i += stride) atomicAdd(&cnt[idx[i]], 1);
}

// ---------------- CSR build: exclusive scan (single block) ----------------
__global__ __launch_bounds__(1024) void scan_kernel(
    const int* __restrict__ cnt, int* __restrict__ off,
    int* __restrict__ cur, int N, int E)
{
    __shared__ int part[1024];
    int t = threadIdx.x;
    const int per = (N + 1023) / 1024;
    int s0 = t * per;
    int s = 0;
    for (int i = 0; i < per; i++) { int k = s0 + i; if (k < N) s += cnt[k]; }
    part[t] = s;
    __syncthreads();
    for (int d = 1; d < 1024; d <<= 1) {
        int v = (t >= d) ? part[t - d] : 0;
        __syncthreads();
        part[t] += v;
        __syncthreads();
    }
    int run = (t == 0) ? 0 : part[t - 1];
    for (int i = 0; i < per; i++) {
        int k = s0 + i;
        if (k < N) { off[k] = run; cur[k] = run; run += cnt[k]; }
    }
    if (t == 0) off[N] = E;
}

// ---------------- CSR build: fill edge lists ----------------
__global__ __launch_bounds__(256) void fill_kernel(
    const int* __restrict__ idx, int* __restrict__ cur,
    int* __restrict__ csr, int E)
{
    int i = blockIdx.x * blockDim.x + threadIdx.x;
    int stride = gridDim.x * blockDim.x;
    for (; i < E; i += stride) {
        int n = idx[i];
        int p = atomicAdd(&cur[n], 1);
        csr[p] = i;
    }
}

__device__ __forceinline__ float dot16(const float4* r, const float4* Wv) {
    float s = 0.f;
    #pragma unroll
    for (int q = 0; q < 4; q++)
        s += r[q].x * Wv[q].x + r[q].y * Wv[q].y + r[q].z * Wv[q].z + r[q].w * Wv[q].w;
    return s;
}

// ---------------- fused rbf-linear * gate -> GATHER (no atomics) ----------------
// One wave per node; lane owns features 2l,2l+1. Edges processed 4 per
// iteration: 4 csr loads (same L1 line, broadcast) feed 20 independent VMEM
// loads (4x m float2, 16x rbf float4 broadcast) in flight before one wait.
// NO cross-lane ops in the address chain (R3's ds_bpermute serialization).
__global__ __launch_bounds__(256) void gather_kernel(
    const float* __restrict__ m, const float* __restrict__ rbf,
    const int* __restrict__ csr, const int* __restrict__ off,
    const float* __restrict__ Wrbf, float* __restrict__ A, int N)
{
    int lane = threadIdx.x & 63;
    int w = threadIdx.x >> 6;
    int n = blockIdx.x * 4 + w;
    if (n >= N) return;

    int f0 = lane << 1;
    float4 W0[4], W1[4];
    #pragma unroll
    for (int q = 0; q < 4; q++) {
        W0[q] = *(const float4*)(Wrbf + (size_t)f0 * R + q * 4);
        W1[q] = *(const float4*)(Wrbf + (size_t)(f0 + 1) * R + q * 4);
    }

    float a0 = 0.f, a1 = 0.f;
    int jb = off[n], je = off[n + 1];

    int j = jb;
    for (; j + 4 <= je; j += 4) {
        int e0 = csr[j];
        int e1 = csr[j + 1];
        int e2 = csr[j + 2];
        int e3 = csr[j + 3];
        float2 m0 = *(const float2*)(m + (size_t)e0 * F + f0);
        float2 m1 = *(const float2*)(m + (size_t)e1 * F + f0);
        float2 m2 = *(const float2*)(m + (size_t)e2 * F + f0);
        float2 m3 = *(const float2*)(m + (size_t)e3 * F + f0);
        float4 r0[4], r1[4], r2[4], r3[4];
        #pragma unroll
        for (int q = 0; q < 4; q++) {
            r0[q] = ((const float4*)(rbf + (size_t)e0 * R))[q];
            r1[q] = ((const float4*)(rbf + (size_t)e1 * R))[q];
            r2[q] = ((const float4*)(rbf + (size_t)e2 * R))[q];
            r3[q] = ((const float4*)(rbf + (size_t)e3 * R))[q];
        }
        a0 += dot16(r0, W0) * m0.x;  a1 += dot16(r0, W1) * m0.y;
        a0 += dot16(r1, W0) * m1.x;  a1 += dot16(r1, W1) * m1.y;
        a0 += dot16(r2, W0) * m2.x;  a1 += dot16(r2, W1) * m2.y;
        a0 += dot16(r3, W0) * m3.x;  a1 += dot16(r3, W1) * m3.y;
    }
    for (; j < je; j++) {
        int e0 = csr[j];
        float2 m0 = *(const float2*)(m + (size_t)e0 * F + f0);
        float4 r0[4];
        #pragma unroll
        for (int q = 0; q < 4; q++)
            r0[q] = ((const float4*)(rbf + (size_t)e0 * R))[q];
        a0 += dot16(r0, W0) * m0.x;
        a1 += dot16(r0, W1) * m0.y;
    }

    *(float2*)(A + (size_t)n * F + f0) = make_float2(a0, a1);
}

// ---------------- fused MLP (3 layers) + projection ----------------
// 32 nodes per block, 625 blocks. Weights staged per layer into 64KB LDS;
// activations in 16KB LDS updated IN-PLACE (rows are wave-local -> no
// inter-layer sync needed). 80KB LDS -> 2 blocks/CU.
__global__ __launch_bounds__(256) void mlp_fused(
    const float* __restrict__ A, const float* __restrict__ dW,
    const float* __restrict__ db, const float* __restrict__ Wout,
    float* __restrict__ out, int N)
{
    __shared__ float Ws[F * F];     // 64 KB
    __shared__ float act[NB * F];   // 16 KB
    int t = threadIdx.x;
    int base = blockIdx.x * NB;
    int j = t & 15, i = t >> 4;

    int  n0[2]; bool ok[2];
    #pragma unroll
    for (int k = 0; k < 2; k++) { n0[k] = base + i + 16 * k; ok[k] = n0[k] < N; }

    for (int l = 0; l < 3; l++) {
        __syncthreads();
        for (int s = t; s < F * F / 4; s += 256) {
            int g = s >> 5, c = s & 31;
            float4 v = *(const float4*)(dW + (size_t)l * F * F + g * F + (c << 2));
            *(float4*)(Ws + g * F + ((c ^ (g & 31)) << 2)) = v;
        }
        __syncthreads();

        float acc[2][8];
        #pragma unroll
        for (int k = 0; k < 2; k++)
            #pragma unroll
            for (int mm = 0; mm < 8; mm++) acc[k][mm] = 0.f;

        for (int c = 0; c < 32; c++) {
            int f = c << 2;
            float4 av[2];
            #pragma unroll
            for (int k = 0; k < 2; k++) {
                if (l == 0)
                    av[k] = ok[k] ? *(const float4*)(A + (size_t)n0[k] * F + f)
                                  : make_float4(0.f, 0.f, 0.f, 0.f);
                else
                    av[k] = *(const float4*)(act + (i + 16 * k) * F + f);
            }
            float4 wv[8];
            #pragma unroll
            for (int mm = 0; mm < 8; mm++) {
                int g = j + 16 * mm;
                wv[mm] = *(const float4*)(Ws + g * F + ((c ^ (g & 31)) << 2));
            }
            #pragma unroll
            for (int k = 0; k < 2; k++)
                #pragma unroll
                for (int mm = 0; mm < 8; mm++)
                    acc[k][mm] += av[k].x * wv[mm].x + av[k].y * wv[mm].y +
                                  av[k].z * wv[mm].z + av[k].w * wv[mm].w;
        }

        #pragma unroll
        for (int mm = 0; mm < 8; mm++) {
            int g = j + 16 * mm;
            float bias = db[l * F + g];
            #pragma unroll
            for (int k = 0; k < 2; k++) {
                float x = acc[k][mm] + bias;
                act[(i + 16 * k) * F + g] = x / (1.f + __expf(-x));
            }
        }
    }

    // ---- projection ----
    __syncthreads();
    for (int s = t; s < O * F / 4; s += 256)
        ((float4*)Ws)[s] = ((const float4*)Wout)[s];
    __syncthreads();

    int nl = t >> 3;                 // 0..31
    int oq = t & 7;
    int n = base + nl;
    if (n < N) {
        float s0 = 0.f, s1 = 0.f;
        for (int f = 0; f < F; f += 4) {
            float4 a  = *(const float4*)(act + nl * F + f);
            float4 w0 = *(const float4*)(Ws + oq * F + f);
            s0 += a.x * w0.x + a.y * w0.y + a.z * w0.z + a.w * w0.w;
            if (oq < 4) {
                float4 w1 = *(const float4*)(Ws + (8 + oq) * F + f);
                s1 += a.x * w1.x + a.y * w1.y + a.z * w1.z + a.w * w1.w;
            }
        }
        out[(size_t)n * O + oq] = s0;
        if (oq < 4) out[(size_t)n * O + 8 + oq] = s1;
    }
}

extern "C" void kernel_launch(void* const* d_in, const int* in_sizes, int n_in,
                              void* d_out, int out_size, void* d_ws, size_t ws_size,
                              hipStream_t stream)
{
    const float* m    = (const float*)d_in[0];
    const float* rbf  = (const float*)d_in[1];
    const int*   aei  = (const int*)d_in[2];
    const float* Wrbf = (const float*)d_in[3];
    const float* dW   = (const float*)d_in[4];
    const float* db   = (const float*)d_in[5];
    const float* Wout = (const float*)d_in[6];
    float* out = (float*)d_out;

    int E = in_sizes[0] / F;     // 640000
    int N = out_size / O;        // 20000

    float* A = (float*)d_ws;
    int* csr = (int*)(A + (size_t)N * F);
    int* cnt = csr + E;
    int* cur = cnt + N;
    int* off = cur + N;

    const int* idx1 = aei + E;   // row 1 = receiving atoms

    zero_int_kernel<<<(N + 255) / 256, 256, 0, stream>>>(cnt, N);
    hist_kernel<<<1024, 256, 0, stream>>>(idx1, cnt, E);
    scan_kernel<<<1, 1024, 0, stream>>>(cnt, off, cur, N, E);
    fill_kernel<<<1024, 256, 0, stream>>>(idx1, cur, csr, E);
    gather_kernel<<<(N + 3) / 4, 256, 0, stream>>>(m, rbf, csr, off, Wrbf, A, N);

    mlp_fused<<<(N + NB - 1) / NB, 256, 0, stream>>>(A, dW, db, Wout, out, N);
}